// Round 4
// baseline (29.022 us; speedup 1.0000x reference)
//
#include <hip/hip_runtime.h>

#define HH 2048
#define WW 2048
#define OH 512
#define OW 512
#define TKC 32             // output cols per tile (threads x)
#define TKR 8              // output rows per tile (threads y)
#define ROWS 38            // 4*TKR + 6 halo rows
#define PITCHF 144         // 16-float lead pad + 128; rows = 576 B = 9 aligned lines
#define V4PR 36            // PITCHF/4
#define NV4 (ROWS * V4PR)  // 1368 float4 per tile buffer (21.9 KB)
#define NBLK 512           // 2 blocks/CU, all resident
#define TPB 6              // tiles per block; 512*6 = 3072 = 3ch * 64 * 16
#define CTILES 16
#define PERCH 1024

// raw barrier + counted vmcnt (T3+T4): loads never drained to 0 mid-loop
#define BAR()    __builtin_amdgcn_s_barrier()
#define SCHED0() __builtin_amdgcn_sched_barrier(0)
#define WAITV(n) asm volatile("s_waitcnt vmcnt(" #n ")" ::: "memory")

__device__ __forceinline__ float rfl(float v) {
    return __int_as_float(__builtin_amdgcn_readfirstlane(__float_as_int(v)));
}

__global__ __launch_bounds__(256, 2)
void wpt2_kernel(const float* __restrict__ x,
                 const float* __restrict__ dec_lo,
                 const float* __restrict__ dec_hi,
                 float* __restrict__ out) {
    __shared__ float bufA[NV4 * 4];
    __shared__ float bufB[NV4 * 4];
    __shared__ float bufC[NV4 * 4];

    const int tx  = threadIdx.x;          // 0..31
    const int ty  = threadIdx.y;          // 0..7
    const int tid = ty * TKC + tx;

    // bijective XCD swizzle (512 % 8 == 0): 64 consecutive work-chunks per XCD
    const int bid = blockIdx.x;
    const int swz = (bid & 7) * (NBLK / 8) + (bid >> 3);
    const int tile0 = swz * TPB;

    // ---- composed 10-tap filters (graycode band order), pinned to SGPRs ----
    float lo[4], hi[4];
#pragma unroll
    for (int j = 0; j < 4; ++j) { lo[j] = dec_lo[j]; hi[j] = dec_hi[j]; }
    float F[4][10];
#pragma unroll
    for (int g = 0; g < 4; ++g) {
        const float* f1 = (g >= 2) ? hi : lo;             // level-1: 0,0,1,1
        const float* f2 = (g == 1 || g == 2) ? hi : lo;   // level-2: 0,1,1,0
#pragma unroll
        for (int d = 0; d < 10; ++d) F[g][d] = 0.f;
#pragma unroll
        for (int j2 = 0; j2 < 4; ++j2)
#pragma unroll
            for (int j1 = 0; j1 < 4; ++j1)
                F[g][2 * j2 + j1] = fmaf(f2[j2], f1[j1], F[g][2 * j2 + j1]);
    }
#pragma unroll
    for (int g = 0; g < 4; ++g)
#pragma unroll
        for (int d = 0; d < 10; ++d) F[g][d] = rfl(F[g][d]);

    // ---- async stage one tile (linear LDS, global_load_lds x16B; 5-6 per wave) ----
    auto stage = [&](float* dst, int tileId) {
        const int ch  = tileId >> 10;
        const int rem = tileId & (PERCH - 1);
        const int trr = rem >> 4;
        const int tcc = rem & (CTILES - 1);
        const float* xc = x + (size_t)ch * HH * WW;
        const int r0 = 32 * trr - 6;
        const int c0 = 128 * tcc - 16;
#pragma unroll
        for (int j = 0; j < 6; ++j) {
            const int i = j * 256 + tid;
            if (j < 5 || i < NV4) {
                const int rr = i / V4PR;
                const int vc = i - rr * V4PR;
                int gr = r0 + rr;      if (gr < 0) gr += HH;   // whole-row wrap only
                int gc = c0 + 4 * vc;  if (gc < 0) gc += WW;   // whole-vec4 wrap only
                __builtin_amdgcn_global_load_lds(
                    (const __attribute__((address_space(1))) void*)&xc[(size_t)gr * WW + gc],
                    (__attribute__((address_space(3))) void*)&dst[i * 4],
                    16, 0, 0);
            }
        }
    };

    // ---- compute one tile (exactly 16 global stores per thread) ----
    auto compute = [&](const float* buf, int tileId) {
        const int ch  = tileId >> 10;
        const int rem = tileId & (PERCH - 1);
        const int trr = rem >> 4;
        const int tcc = rem & (CTILES - 1);

        float t[4][10];
#pragma unroll
        for (int g = 0; g < 4; ++g)
#pragma unroll
            for (int d = 0; d < 10; ++d) t[g][d] = 0.f;

#pragma unroll
        for (int u = 0; u < 10; ++u) {
            const float* rp = &buf[(4 * ty + u) * PITCHF + 4 * tx + 8];
            const float4 a = *reinterpret_cast<const float4*>(rp);
            const float4 b = *reinterpret_cast<const float4*>(rp + 4);
            const float4 c = *reinterpret_cast<const float4*>(rp + 8);
            const float row[12] = {a.x, a.y, a.z, a.w, b.x, b.y, b.z, b.w,
                                   c.x, c.y, c.z, c.w};
            const int dr = 9 - u;
#pragma unroll
            for (int dc = 0; dc < 10; ++dc) {
                const float v = row[11 - dc];
#pragma unroll
                for (int g = 0; g < 4; ++g)
                    t[g][dc] = fmaf(F[g][dr], v, t[g][dc]);
            }
        }

        const int kr = TKR * trr + ty;
        const int kc = TKC * tcc + tx;
        const size_t plane = (size_t)OH * OW;
        const size_t obase = (size_t)(ch * 16) * plane + (size_t)kr * OW + kc;
#pragma unroll
        for (int gi = 0; gi < 4; ++gi) {
#pragma unroll
            for (int gj = 0; gj < 4; ++gj) {
                float acc = 0.f;
#pragma unroll
                for (int dc = 0; dc < 10; ++dc)
                    acc = fmaf(F[gj][dc], t[gi][dc], acc);
                out[obase + (size_t)(gi * 4 + gj) * plane] = acc;
            }
        }
    };

    // ---- depth-2 pipeline, 3 static buffers, counted vmcnt ----
    // Per-wave VMEM order: L0 L1 | S0 L2 | S1 L3 | S2 L4 | S3 L5 | S4 | S5
    // (L = 5-6 tile loads, S = exactly 16 stores). Before compute(ti) need Li
    // drained; newer ops = 16 + k_next >= 21 in steady state.
    stage(bufA, tile0 + 0);
    stage(bufB, tile0 + 1);

    WAITV(5);  BAR(); SCHED0(); compute(bufA, tile0 + 0); stage(bufC, tile0 + 2);
    WAITV(21); BAR(); SCHED0(); compute(bufB, tile0 + 1); stage(bufA, tile0 + 3);
    WAITV(21); BAR(); SCHED0(); compute(bufC, tile0 + 2); stage(bufB, tile0 + 4);
    WAITV(21); BAR(); SCHED0(); compute(bufA, tile0 + 3); stage(bufC, tile0 + 5);
    WAITV(21); BAR(); SCHED0(); compute(bufB, tile0 + 4);
    WAITV(16); BAR(); SCHED0(); compute(bufC, tile0 + 5);
}

extern "C" void kernel_launch(void* const* d_in, const int* in_sizes, int n_in,
                              void* d_out, int out_size, void* d_ws, size_t ws_size,
                              hipStream_t stream) {
    const float* x      = (const float*)d_in[0];
    const float* dec_lo = (const float*)d_in[1];
    const float* dec_hi = (const float*)d_in[2];
    float* out          = (float*)d_out;

    hipLaunchKernelGGL(wpt2_kernel, dim3(NBLK), dim3(TKC, TKR), 0, stream,
                       x, dec_lo, dec_hi, out);
}

// Round 5
// 25.849 us; speedup vs baseline: 1.1227x; 1.1227x over previous
//
#include <hip/hip_runtime.h>

#define HH 2048
#define WW 2048
#define OH 512
#define OW 512
#define TKC 32             // output cols per tile (threads x)
#define TKR 8              // output rows per tile (threads y)
#define ROWS 38            // 4*TKR + 6 halo rows
#define PITCHF 144         // 16-float lead pad + 128; rows = 576 B, 64B-aligned
#define V4PR 36            // PITCHF/4
#define NV4 (ROWS * V4PR)  // 1368 float4 per tile buffer (21.9 KB)
#define NBLK 768           // 3 blocks/CU, all resident
#define TPB 4              // vertical stack of 4 tiles; 768*4 = 3072 tiles

#define BAR()    __builtin_amdgcn_s_barrier()
#define SCHED0() __builtin_amdgcn_sched_barrier(0)
#define WAITV(n) asm volatile("s_waitcnt vmcnt(" #n ")" ::: "memory")

__device__ __forceinline__ float rfl(float v) {
    return __int_as_float(__builtin_amdgcn_readfirstlane(__float_as_int(v)));
}

__global__ __launch_bounds__(256, 3)
void wpt2_kernel(const float* __restrict__ x,
                 const float* __restrict__ dec_lo,
                 const float* __restrict__ dec_hi,
                 float* __restrict__ out) {
    __shared__ float bufA[NV4 * 4];
    __shared__ float bufB[NV4 * 4];

    const int tx  = threadIdx.x;          // 0..31
    const int ty  = threadIdx.y;          // 0..7
    const int tid = ty * TKC + tx;

    // bijective XCD swizzle (768 % 8 == 0): consecutive swz -> consecutive tcc
    const int bid = blockIdx.x;
    const int swz = (bid & 7) * (NBLK / 8) + (bid >> 3);
    // vertical stacking: ch, col-tile, base row-tile (4 consecutive trr)
    const int ch   = swz >> 8;
    const int rem  = swz & 255;
    const int tcc  = rem & 15;
    const int trr0 = (rem >> 4) * TPB;

    // ---- composed 10-tap filters (graycode band order), pinned to SGPRs ----
    float lo[4], hi[4];
#pragma unroll
    for (int j = 0; j < 4; ++j) { lo[j] = dec_lo[j]; hi[j] = dec_hi[j]; }
    float F[4][10];
#pragma unroll
    for (int g = 0; g < 4; ++g) {
        const float* f1 = (g >= 2) ? hi : lo;             // level-1: 0,0,1,1
        const float* f2 = (g == 1 || g == 2) ? hi : lo;   // level-2: 0,1,1,0
#pragma unroll
        for (int d = 0; d < 10; ++d) F[g][d] = 0.f;
#pragma unroll
        for (int j2 = 0; j2 < 4; ++j2)
#pragma unroll
            for (int j1 = 0; j1 < 4; ++j1)
                F[g][2 * j2 + j1] = fmaf(f2[j2], f1[j1], F[g][2 * j2 + j1]);
    }
#pragma unroll
    for (int g = 0; g < 4; ++g)
#pragma unroll
        for (int d = 0; d < 10; ++d) F[g][d] = rfl(F[g][d]);

    const float* xc = x + (size_t)ch * HH * WW;

    // ---- async stage one tile (linear LDS, global_load_lds x16B; 5-6/lane) ----
    auto stage = [&](float* dst, int trr) {
        const int r0 = 32 * trr - 6;
        const int c0 = 128 * tcc - 16;
#pragma unroll
        for (int j = 0; j < 6; ++j) {
            const int i = j * 256 + tid;
            if (j < 5 || i < NV4) {
                const int rr = i / V4PR;
                const int vc = i - rr * V4PR;
                int gr = r0 + rr;      if (gr < 0) gr += HH;   // whole-row wrap only
                int gc = c0 + 4 * vc;  if (gc < 0) gc += WW;   // whole-vec4 wrap only
                __builtin_amdgcn_global_load_lds(
                    (const __attribute__((address_space(1))) void*)&xc[(size_t)gr * WW + gc],
                    (__attribute__((address_space(3))) void*)&dst[i * 4],
                    16, 0, 0);
            }
        }
    };

    // ---- compute one tile (exactly 16 nontemporal stores per thread) ----
    auto compute = [&](const float* buf, int trr) {
        float t[4][10];
#pragma unroll
        for (int g = 0; g < 4; ++g)
#pragma unroll
            for (int d = 0; d < 10; ++d) t[g][d] = 0.f;

#pragma unroll
        for (int u = 0; u < 10; ++u) {
            const float* rp = &buf[(4 * ty + u) * PITCHF + 4 * tx + 8];
            const float4 a = *reinterpret_cast<const float4*>(rp);
            const float4 b = *reinterpret_cast<const float4*>(rp + 4);
            const float4 c = *reinterpret_cast<const float4*>(rp + 8);
            const float row[12] = {a.x, a.y, a.z, a.w, b.x, b.y, b.z, b.w,
                                   c.x, c.y, c.z, c.w};
            const int dr = 9 - u;
#pragma unroll
            for (int dc = 0; dc < 10; ++dc) {
                const float v = row[11 - dc];
#pragma unroll
                for (int g = 0; g < 4; ++g)
                    t[g][dc] = fmaf(F[g][dr], v, t[g][dc]);
            }
        }

        const int kr = TKR * trr + ty;
        const int kc = TKC * tcc + tx;
        const size_t plane = (size_t)OH * OW;
        float* op = out + (size_t)(ch * 16) * plane + (size_t)kr * OW + kc;
#pragma unroll
        for (int gi = 0; gi < 4; ++gi) {
#pragma unroll
            for (int gj = 0; gj < 4; ++gj) {
                float acc = 0.f;
#pragma unroll
                for (int dc = 0; dc < 10; ++dc)
                    acc = fmaf(F[gj][dc], t[gi][dc], acc);
                __builtin_nontemporal_store(acc, op + (size_t)(gi * 4 + gj) * plane);
            }
        }
    };

    // ---- depth-1 double-buffer, counted vmcnt: never wait on store-acks ----
    // Per-wave VMEM order: L0 | L1 S0 | L2 S1 | L3 S2 | S3
    // Before compute(ti): need Li drained; newer ops = 16 stores -> vmcnt(16).
    stage(bufA, trr0 + 0);
    WAITV(0);  BAR(); SCHED0();
    stage(bufB, trr0 + 1); compute(bufA, trr0 + 0);
    WAITV(16); BAR(); SCHED0();
    stage(bufA, trr0 + 2); compute(bufB, trr0 + 1);
    WAITV(16); BAR(); SCHED0();
    stage(bufB, trr0 + 3); compute(bufA, trr0 + 2);
    WAITV(16); BAR(); SCHED0();
    compute(bufB, trr0 + 3);
}

extern "C" void kernel_launch(void* const* d_in, const int* in_sizes, int n_in,
                              void* d_out, int out_size, void* d_ws, size_t ws_size,
                              hipStream_t stream) {
    const float* x      = (const float*)d_in[0];
    const float* dec_lo = (const float*)d_in[1];
    const float* dec_hi = (const float*)d_in[2];
    float* out          = (float*)d_out;

    hipLaunchKernelGGL(wpt2_kernel, dim3(NBLK), dim3(TKC, TKR), 0, stream,
                       x, dec_lo, dec_hi, out);
}

// Round 6
// 24.873 us; speedup vs baseline: 1.1668x; 1.0393x over previous
//
#include <hip/hip_runtime.h>

#define HH 2048
#define WW 2048
#define OH 512
#define OW 512
#define TKC 32             // output cols per tile (threads x)
#define TKR 16             // output rows per tile (threads y)
#define ROWS 70            // 4*TKR + 6 halo rows
#define PITCHF 144         // 16-float lead pad + 128; rows = 576 B, 64B-aligned
#define V4PR 36            // PITCHF/4
#define NV4 (ROWS * V4PR)  // 2520 float4 per tile buffer (39.4 KB)
#define NBLK 512           // 2 blocks/CU (LDS: 78.75 KB/block), all resident
#define TPB 3              // tiles per block; 512*3 = 1536 = 3ch * 32trr * 16tcc

#define BAR()    __builtin_amdgcn_s_barrier()
#define SCHED0() __builtin_amdgcn_sched_barrier(0)
#define WAITV(n) asm volatile("s_waitcnt vmcnt(" #n ")" ::: "memory")

__device__ __forceinline__ float rfl(float v) {
    return __int_as_float(__builtin_amdgcn_readfirstlane(__float_as_int(v)));
}

__global__ __launch_bounds__(512, 4)
void wpt2_kernel(const float* __restrict__ x,
                 const float* __restrict__ dec_lo,
                 const float* __restrict__ dec_hi,
                 float* __restrict__ out) {
    __shared__ float bufA[NV4 * 4];
    __shared__ float bufB[NV4 * 4];

    const int tx  = threadIdx.x;          // 0..31
    const int ty  = threadIdx.y;          // 0..15
    const int tid = ty * TKC + tx;

    // bijective XCD swizzle (512 % 8 == 0): each XCD gets 64 consecutive chunks
    const int bid = blockIdx.x;
    const int swz = (bid & 7) * (NBLK / 8) + (bid >> 3);
    const int tile0 = swz * TPB;   // tileId = (ch*16 + tcc)*32 + trr (trr innermost)

    // ---- composed 10-tap filters (graycode band order), pinned to SGPRs ----
    float lo[4], hi[4];
#pragma unroll
    for (int j = 0; j < 4; ++j) { lo[j] = dec_lo[j]; hi[j] = dec_hi[j]; }
    float F[4][10];
#pragma unroll
    for (int g = 0; g < 4; ++g) {
        const float* f1 = (g >= 2) ? hi : lo;             // level-1: 0,0,1,1
        const float* f2 = (g == 1 || g == 2) ? hi : lo;   // level-2: 0,1,1,0
#pragma unroll
        for (int d = 0; d < 10; ++d) F[g][d] = 0.f;
#pragma unroll
        for (int j2 = 0; j2 < 4; ++j2)
#pragma unroll
            for (int j1 = 0; j1 < 4; ++j1)
                F[g][2 * j2 + j1] = fmaf(f2[j2], f1[j1], F[g][2 * j2 + j1]);
    }
#pragma unroll
    for (int g = 0; g < 4; ++g)
#pragma unroll
        for (int d = 0; d < 10; ++d) F[g][d] = rfl(F[g][d]);

    // ---- async stage one tile (linear LDS, global_load_lds x16B; 5/lane) ----
    auto stage = [&](float* dst, int tileId) {
        const int ch  = tileId >> 9;
        const int rem = tileId & 511;
        const int tcc = rem >> 5;
        const int trr = rem & 31;
        const float* xc = x + (size_t)ch * HH * WW;
        const int r0 = 64 * trr - 6;
        const int c0 = 128 * tcc - 16;
#pragma unroll
        for (int j = 0; j < 5; ++j) {
            const int i = j * 512 + tid;
            if (j < 4 || i < NV4) {
                const int rr = i / V4PR;
                const int vc = i - rr * V4PR;
                int gr = r0 + rr;      if (gr < 0) gr += HH;   // whole-row wrap only
                int gc = c0 + 4 * vc;  if (gc < 0) gc += WW;   // whole-vec4 wrap only
                __builtin_amdgcn_global_load_lds(
                    (const __attribute__((address_space(1))) void*)&xc[(size_t)gr * WW + gc],
                    (__attribute__((address_space(3))) void*)&dst[i * 4],
                    16, 0, 0);
            }
        }
    };

    // ---- compute one tile (exactly 16 nontemporal stores per thread) ----
    auto compute = [&](const float* buf, int tileId) {
        const int ch  = tileId >> 9;
        const int rem = tileId & 511;
        const int tcc = rem >> 5;
        const int trr = rem & 31;

        float t[4][10];
#pragma unroll
        for (int g = 0; g < 4; ++g)
#pragma unroll
            for (int d = 0; d < 10; ++d) t[g][d] = 0.f;

#pragma unroll
        for (int u = 0; u < 10; ++u) {
            const float* rp = &buf[(4 * ty + u) * PITCHF + 4 * tx + 8];
            const float4 a = *reinterpret_cast<const float4*>(rp);
            const float4 b = *reinterpret_cast<const float4*>(rp + 4);
            const float4 c = *reinterpret_cast<const float4*>(rp + 8);
            const float row[12] = {a.x, a.y, a.z, a.w, b.x, b.y, b.z, b.w,
                                   c.x, c.y, c.z, c.w};
            const int dr = 9 - u;
#pragma unroll
            for (int dc = 0; dc < 10; ++dc) {
                const float v = row[11 - dc];
#pragma unroll
                for (int g = 0; g < 4; ++g)
                    t[g][dc] = fmaf(F[g][dr], v, t[g][dc]);
            }
        }

        const int kr = TKR * trr + ty;
        const int kc = TKC * tcc + tx;
        const size_t plane = (size_t)OH * OW;
        float* op = out + (size_t)(ch * 16) * plane + (size_t)kr * OW + kc;
#pragma unroll
        for (int gi = 0; gi < 4; ++gi) {
#pragma unroll
            for (int gj = 0; gj < 4; ++gj) {
                float acc = 0.f;
#pragma unroll
                for (int dc = 0; dc < 10; ++dc)
                    acc = fmaf(F[gj][dc], t[gi][dc], acc);
                __builtin_nontemporal_store(acc, op + (size_t)(gi * 4 + gj) * plane);
            }
        }
    };

    // ---- depth-1 double-buffer, counted vmcnt (never wait on store-acks) ----
    // Per-wave VMEM order: L0 | L1 S0 | L2 S1 | S2
    // Before compute(ti): Li must be drained; newer ops = 16 stores -> vmcnt(16).
    stage(bufA, tile0 + 0);
    WAITV(0);  BAR(); SCHED0();
    stage(bufB, tile0 + 1); compute(bufA, tile0 + 0);
    WAITV(16); BAR(); SCHED0();
    stage(bufA, tile0 + 2); compute(bufB, tile0 + 1);
    WAITV(16); BAR(); SCHED0();
    compute(bufA, tile0 + 2);
}

extern "C" void kernel_launch(void* const* d_in, const int* in_sizes, int n_in,
                              void* d_out, int out_size, void* d_ws, size_t ws_size,
                              hipStream_t stream) {
    const float* x      = (const float*)d_in[0];
    const float* dec_lo = (const float*)d_in[1];
    const float* dec_hi = (const float*)d_in[2];
    float* out          = (float*)d_out;

    hipLaunchKernelGGL(wpt2_kernel, dim3(NBLK), dim3(TKC, TKR), 0, stream,
                       x, dec_lo, dec_hi, out);
}

// Round 8
// 24.743 us; speedup vs baseline: 1.1729x; 1.0052x over previous
//
#include <hip/hip_runtime.h>

#define HH 2048
#define WW 2048
#define OH 512
#define OW 512
#define TKC 32             // output cols per tile (threads x)
#define TKR 16             // output rows per tile (threads y)
#define ROWS 70            // 4*TKR + 6 halo rows
#define PITCHF 144         // 16-float lead pad + 128; rows = 576 B = 9 exact lines
#define V4PR 36            // PITCHF/4
#define NV4 (ROWS * V4PR)  // 2520 float4 per tile buffer (39.4 KB)
#define NBLK 512           // 2 blocks/CU (78.75 KB LDS/block), all resident
#define TPB 3              // tiles per block; 512*3 = 1536 = 3ch * 32trr * 16tcc

#define BAR()    __builtin_amdgcn_s_barrier()
#define SCHED0() __builtin_amdgcn_sched_barrier(0)
#define WAITV(n) asm volatile("s_waitcnt vmcnt(" #n ")" ::: "memory")

__device__ __forceinline__ float rfl(float v) {
    return __int_as_float(__builtin_amdgcn_readfirstlane(__float_as_int(v)));
}

__global__ __launch_bounds__(512, 4)
void wpt2_kernel(const float* __restrict__ x,
                 const float* __restrict__ dec_lo,
                 const float* __restrict__ dec_hi,
                 float* __restrict__ out) {
    __shared__ float bufA[NV4 * 4];
    __shared__ float bufB[NV4 * 4];

    const int tx  = threadIdx.x;          // 0..31
    const int ty  = threadIdx.y;          // 0..15
    const int tid = ty * TKC + tx;

    // bijective XCD swizzle (512 % 8 == 0): each XCD gets 64 consecutive chunks
    const int bid = blockIdx.x;
    const int swz = (bid & 7) * (NBLK / 8) + (bid >> 3);
    const int tile0 = swz * TPB;   // tileId = (ch*16 + tcc)*32 + trr (trr innermost)

    // ---- composed 10-tap filters (graycode band order), pinned to SGPRs ----
    float lo[4], hi[4];
#pragma unroll
    for (int j = 0; j < 4; ++j) { lo[j] = dec_lo[j]; hi[j] = dec_hi[j]; }
    float F[4][10];
#pragma unroll
    for (int g = 0; g < 4; ++g) {
        const float* f1 = (g >= 2) ? hi : lo;             // level-1: 0,0,1,1
        const float* f2 = (g == 1 || g == 2) ? hi : lo;   // level-2: 0,1,1,0
#pragma unroll
        for (int d = 0; d < 10; ++d) F[g][d] = 0.f;
#pragma unroll
        for (int j2 = 0; j2 < 4; ++j2)
#pragma unroll
            for (int j1 = 0; j1 < 4; ++j1)
                F[g][2 * j2 + j1] = fmaf(f2[j2], f1[j1], F[g][2 * j2 + j1]);
    }
#pragma unroll
    for (int g = 0; g < 4; ++g)
#pragma unroll
        for (int d = 0; d < 10; ++d) F[g][d] = rfl(F[g][d]);

    // ---- async stage one tile (linear LDS, global_load_lds x16B; 5/lane) ----
    // covers cols [128tcc-16, 128tcc+127]: ends exactly at tile edge, no overhang
    auto stage = [&](float* dst, int tileId) {
        const int ch  = tileId >> 9;
        const int rem = tileId & 511;
        const int tcc = rem >> 5;
        const int trr = rem & 31;
        const float* xc = x + (size_t)ch * HH * WW;
        const int r0 = 64 * trr - 6;
        const int c0 = 128 * tcc - 16;
#pragma unroll
        for (int j = 0; j < 5; ++j) {
            const int i = j * 512 + tid;
            if (j < 4 || i < NV4) {
                const int rr = i / V4PR;
                const int vc = i - rr * V4PR;
                int gr = r0 + rr;      if (gr < 0) gr += HH;   // whole-row wrap only
                int gc = c0 + 4 * vc;  if (gc < 0) gc += WW;   // whole-vec4 wrap only
                __builtin_amdgcn_global_load_lds(
                    (const __attribute__((address_space(1))) void*)&xc[(size_t)gr * WW + gc],
                    (__attribute__((address_space(3))) void*)&dst[i * 4],
                    16, 0, 0);
            }
        }
    };

    // ---- compute one tile (exactly 16 nontemporal stores per thread) ----
    auto compute = [&](const float* buf, int tileId) {
        const int ch  = tileId >> 9;
        const int rem = tileId & 511;
        const int tcc = rem >> 5;
        const int trr = rem & 31;

        __builtin_amdgcn_s_setprio(1);
        float t[4][10];
#pragma unroll
        for (int g = 0; g < 4; ++g)
#pragma unroll
            for (int d = 0; d < 10; ++d) t[g][d] = 0.f;

#pragma unroll
        for (int u = 0; u < 10; ++u) {
            const float* rp = &buf[(4 * ty + u) * PITCHF + 4 * tx + 8];
            const float4 a = *reinterpret_cast<const float4*>(rp);
            const float4 b = *reinterpret_cast<const float4*>(rp + 4);
            const float4 c = *reinterpret_cast<const float4*>(rp + 8);
            const float row[12] = {a.x, a.y, a.z, a.w, b.x, b.y, b.z, b.w,
                                   c.x, c.y, c.z, c.w};
            const int dr = 9 - u;
#pragma unroll
            for (int dc = 0; dc < 10; ++dc) {
                const float v = row[11 - dc];
#pragma unroll
                for (int g = 0; g < 4; ++g)
                    t[g][dc] = fmaf(F[g][dr], v, t[g][dc]);
            }
        }

        const int kr = TKR * trr + ty;
        const int kc = TKC * tcc + tx;
        const size_t plane = (size_t)OH * OW;
        float* op = out + (size_t)(ch * 16) * plane + (size_t)kr * OW + kc;
#pragma unroll
        for (int gi = 0; gi < 4; ++gi) {
#pragma unroll
            for (int gj = 0; gj < 4; ++gj) {
                float acc = 0.f;
#pragma unroll
                for (int dc = 0; dc < 10; ++dc)
                    acc = fmaf(F[gj][dc], t[gi][dc], acc);
                __builtin_nontemporal_store(acc, op + (size_t)(gi * 4 + gj) * plane);
            }
        }
        __builtin_amdgcn_s_setprio(0);
    };

    // ---- depth-1 double-buffer, counted vmcnt (never wait on store-acks) ----
    // Per-wave VMEM order: L0 | L1 S0 | L2 S1 | S2
    // Before compute(ti): Li must be drained; newer ops = 16 stores -> vmcnt(16).
    stage(bufA, tile0 + 0);
    WAITV(0);  BAR(); SCHED0();
    stage(bufB, tile0 + 1); compute(bufA, tile0 + 0);
    WAITV(16); BAR(); SCHED0();
    stage(bufA, tile0 + 2); compute(bufB, tile0 + 1);
    WAITV(16); BAR(); SCHED0();
    compute(bufA, tile0 + 2);
}

extern "C" void kernel_launch(void* const* d_in, const int* in_sizes, int n_in,
                              void* d_out, int out_size, void* d_ws, size_t ws_size,
                              hipStream_t stream) {
    const float* x      = (const float*)d_in[0];
    const float* dec_lo = (const float*)d_in[1];
    const float* dec_hi = (const float*)d_in[2];
    float* out          = (float*)d_out;

    hipLaunchKernelGGL(wpt2_kernel, dim3(NBLK), dim3(TKC, TKR), 0, stream,
                       x, dec_lo, dec_hi, out);
}